// Round 5
// baseline (105.320 us; speedup 1.0000x reference)
//
#include <hip/hip_runtime.h>
#include <hip/hip_bf16.h>
#include <hip/hip_cooperative_groups.h>

namespace cg = cooperative_groups;

// SOM layer: out[b] = mean_p ||x_b - proto_p||^2
//          = ||x_b||^2 + (1/P)*sum_p||p||^2 - (2/P)*dot(x_b, colsum)
// B=8192, P=1024, D=256, all fp32.
//
// Single cooperative kernel, 256 blocks x 256 thr (1 block/CU):
//   Phase 0: every block loads its 32 x-rows into registers (held across
//            grid.sync) and computes ||x||^2 per row.
//   Phase 1: blocks 0..31 compute proto partials -> ws (agent-scope stores;
//            round-3 post-mortem: per-XCD L2s are not cross-coherent, the
//            handoff must go through the LLC coherence point).
//   grid.sync()
//   Phase 2: every block reduces the 32 partials (LLC-hot) and finishes
//            dot(x,colsum) from the held registers. x is read exactly once.
//
// ws layout (floats): ws[g*256+d] g=0..31 partial colsums; ws[32*256+g] sq.

#define SOM_B  8192
#define SOM_P  1024
#define SOM_D  256
#define NPART  32
#define NBLK   256
#define RPB    (SOM_B / NBLK)   // 32 rows per block
#define RPW    (RPB / 4)        // 8 rows per wave

__device__ __forceinline__ void ws_store(float* p, float v) {
    __hip_atomic_store(p, v, __ATOMIC_RELAXED, __HIP_MEMORY_SCOPE_AGENT);
}
__device__ __forceinline__ float ws_load(const float* p) {
    return __hip_atomic_load(p, __ATOMIC_RELAXED, __HIP_MEMORY_SCOPE_AGENT);
}

__global__ __launch_bounds__(256) void som_fused(
    const float* __restrict__ x, const float* __restrict__ proto,
    float* __restrict__ ws, float* __restrict__ out) {
    const int t    = threadIdx.x;
    const int lane = t & 63;
    const int wv   = t >> 6;                       // 0..3
    const int blk  = blockIdx.x;

    // ---- Phase 0: register-load 32 x-rows (8/wave), compute ||x||^2 ----
    const float4* x4 = (const float4*)x;           // 64 float4 per row
    const int row0 = blk * RPB + wv * RPW;
    float4 xv[RPW];
    float  sq[RPW];
#pragma unroll
    for (int i = 0; i < RPW; ++i) {
        xv[i] = x4[(size_t)(row0 + i) * 64 + lane];
        sq[i] = xv[i].x * xv[i].x + xv[i].y * xv[i].y
              + xv[i].z * xv[i].z + xv[i].w * xv[i].w;
    }

    // ---- Phase 1: blocks 0..31 produce proto partials ----
    __shared__ float4 lds_cs[4][64];
    __shared__ float  lds_sq[4];
    if (blk < NPART) {
        const float4* p4 = (const float4*)proto;
        const int prow0 = blk * 32 + wv * 8;
        float4 cs = {0.f, 0.f, 0.f, 0.f};
        float  psq = 0.f;
#pragma unroll
        for (int i = 0; i < 8; ++i) {
            float4 v = p4[(size_t)(prow0 + i) * 64 + lane];
            cs.x += v.x; cs.y += v.y; cs.z += v.z; cs.w += v.w;
            psq  += v.x * v.x + v.y * v.y + v.z * v.z + v.w * v.w;
        }
#pragma unroll
        for (int off = 32; off; off >>= 1) psq += __shfl_down(psq, off, 64);
        if (lane == 0) lds_sq[wv] = psq;
        lds_cs[wv][lane] = cs;
        __syncthreads();
        if (t < 64) {
            float4 a = lds_cs[0][lane], b = lds_cs[1][lane];
            float4 c = lds_cs[2][lane], d = lds_cs[3][lane];
            float* base = ws + (size_t)blk * SOM_D + lane * 4;
            ws_store(base + 0, (a.x + b.x) + (c.x + d.x));
            ws_store(base + 1, (a.y + b.y) + (c.y + d.y));
            ws_store(base + 2, (a.z + b.z) + (c.z + d.z));
            ws_store(base + 3, (a.w + b.w) + (c.w + d.w));
            if (lane == 0)
                ws_store(&ws[NPART * SOM_D + blk],
                         (lds_sq[0] + lds_sq[1]) + (lds_sq[2] + lds_sq[3]));
        }
    }

    cg::this_grid().sync();

    // ---- Phase 2: reduce partials (LLC-hot), finish rows from registers ---
    __shared__ float cs[SOM_D];
    __shared__ float sqp_lds;
    {
        float c = 0.f;
#pragma unroll
        for (int g = 0; g < NPART; ++g) c += ws_load(&ws[g * SOM_D + t]);
        cs[t] = c;
    }
    if (t < 32) {
        float s = ws_load(&ws[NPART * SOM_D + t]);
#pragma unroll
        for (int off = 16; off; off >>= 1) s += __shfl_down(s, off, 32);
        if (t == 0) sqp_lds = s;
    }
    __syncthreads();

    const float  sqp = sqp_lds;
    const float4 mv  = ((const float4*)cs)[lane];
    float dt[RPW];
#pragma unroll
    for (int i = 0; i < RPW; ++i)
        dt[i] = xv[i].x * mv.x + xv[i].y * mv.y
              + xv[i].z * mv.z + xv[i].w * mv.w;
#pragma unroll
    for (int i = 0; i < RPW; ++i) {
#pragma unroll
        for (int off = 32; off; off >>= 1) {
            sq[i] += __shfl_down(sq[i], off, 64);
            dt[i] += __shfl_down(dt[i], off, 64);
        }
    }
    if (lane == 0) {
        const float invP = 1.0f / (float)SOM_P;
#pragma unroll
        for (int i = 0; i < RPW; ++i)
            out[row0 + i] = sq[i] + (sqp - 2.0f * dt[i]) * invP;
    }
}

extern "C" void kernel_launch(void* const* d_in, const int* in_sizes, int n_in,
                              void* d_out, int out_size, void* d_ws, size_t ws_size,
                              hipStream_t stream) {
    const float* x     = (const float*)d_in[0];   // (B, D) fp32
    const float* proto = (const float*)d_in[1];   // (P, D) fp32
    float* out = (float*)d_out;                   // (B,)  fp32
    float* ws  = (float*)d_ws;                    // partials (~33 KB used)

    void* args[] = {(void*)&x, (void*)&proto, (void*)&ws, (void*)&out};
    hipLaunchCooperativeKernel((const void*)som_fused, dim3(NBLK), dim3(256),
                               args, 0, stream);
}

// Round 6
// 78.832 us; speedup vs baseline: 1.3360x; 1.3360x over previous
//
#include <hip/hip_runtime.h>
#include <hip/hip_bf16.h>

// SOM layer: out[b] = mean_p ||x_b - proto_p||^2
//          = ||x_b||^2 + (1/P)*sum_p||p||^2 - (2/P)*dot(x_b, colsum)
// B=8192, P=1024, D=256, all fp32.
//
// SINGLE ordinary dispatch (R5 post-mortem: cooperative launch in a captured
// graph cost +42 us; R3 post-mortem: cross-kernel ws handoff needs agent-scope
// traffic). This version has NO handoff at all: every block redundantly
// computes the full colsum from proto (read-only input -> no coherence
// hazard, deterministic identical result in every block).
//
// 128 blocks x 1024 threads (16 waves):
//   - block handles 64 x-rows (4 rows/wave), register-held across the sync
//   - proto's 1024 rows split 64/wave -> per-wave partial colsum -> LDS
//   - combine -> colsum[256] + sum(proto^2), then finish rows from registers
// Traffic: proto 1 MB/block from XCD L2 (128 MB aggregate ~ 3.7 us),
// x 8.4 MB HBM (~2 us at half-device), overlapped. d_ws unused.

#define SOM_B  8192
#define SOM_P  1024
#define SOM_D  256
#define NBLK   128
#define NW     16                  // waves per block
#define RPW    4                   // x rows per wave  (NBLK*NW*RPW = 8192)
#define PRW    (SOM_P / NW)        // proto rows per wave = 64

__global__ __launch_bounds__(1024) void som_fused(
    const float* __restrict__ x, const float* __restrict__ proto,
    float* __restrict__ out) {
    const int t    = threadIdx.x;
    const int lane = t & 63;
    const int wv   = t >> 6;                       // 0..15
    const int blk  = blockIdx.x;

    // ---- Phase 0: issue x register loads (HBM stream, overlaps proto) ----
    const float4* x4 = (const float4*)x;           // 64 float4 per row
    const int row0 = blk * (NW * RPW) + wv * RPW;
    float4 xv[RPW];
#pragma unroll
    for (int i = 0; i < RPW; ++i)
        xv[i] = x4[(size_t)(row0 + i) * 64 + lane];

    // ---- Phase 1: per-wave partial colsum over 64 proto rows (L2-hot) ----
    const float4* p4 = (const float4*)proto;
    float4 cs = {0.f, 0.f, 0.f, 0.f};
    float  psq = 0.f;
#pragma unroll 8
    for (int i = 0; i < PRW; ++i) {
        float4 v = p4[(size_t)(wv * PRW + i) * 64 + lane];
        cs.x += v.x; cs.y += v.y; cs.z += v.z; cs.w += v.w;
        psq  += v.x * v.x + v.y * v.y + v.z * v.z + v.w * v.w;
    }

    __shared__ float4 lds_cs[NW][64];              // 16 KB
    __shared__ float  lds_sq[NW];
    __shared__ float  cs_final[SOM_D];             // 1 KB
    __shared__ float  sqp_lds;

#pragma unroll
    for (int off = 32; off; off >>= 1) psq += __shfl_down(psq, off, 64);
    if (lane == 0) lds_sq[wv] = psq;
    lds_cs[wv][lane] = cs;
    __syncthreads();

    // ---- Phase 2: combine 16 wave-partials (threads 0..255, one col each) --
    if (t < SOM_D) {
        const float* f = (const float*)lds_cs;     // [w*256 + col]
        float c = 0.f;
#pragma unroll
        for (int w = 0; w < NW; ++w) c += f[w * SOM_D + t];  // conflict-free
        cs_final[t] = c;
        if (t == 0) {
            float s = 0.f;
#pragma unroll
            for (int w = 0; w < NW; ++w) s += lds_sq[w];
            sqp_lds = s;
        }
    }
    __syncthreads();

    // ---- Phase 3: finish rows from held registers ----
    const float  sqp = sqp_lds;
    const float4 mv  = ((const float4*)cs_final)[lane];
    float sq[RPW], dt[RPW];
#pragma unroll
    for (int i = 0; i < RPW; ++i) {
        sq[i] = xv[i].x * xv[i].x + xv[i].y * xv[i].y
              + xv[i].z * xv[i].z + xv[i].w * xv[i].w;
        dt[i] = xv[i].x * mv.x + xv[i].y * mv.y
              + xv[i].z * mv.z + xv[i].w * mv.w;
    }
#pragma unroll
    for (int i = 0; i < RPW; ++i) {
#pragma unroll
        for (int off = 32; off; off >>= 1) {
            sq[i] += __shfl_down(sq[i], off, 64);
            dt[i] += __shfl_down(dt[i], off, 64);
        }
    }
    if (lane == 0) {
        const float invP = 1.0f / (float)SOM_P;
#pragma unroll
        for (int i = 0; i < RPW; ++i)
            out[row0 + i] = sq[i] + (sqp - 2.0f * dt[i]) * invP;
    }
}

extern "C" void kernel_launch(void* const* d_in, const int* in_sizes, int n_in,
                              void* d_out, int out_size, void* d_ws, size_t ws_size,
                              hipStream_t stream) {
    const float* x     = (const float*)d_in[0];   // (B, D) fp32
    const float* proto = (const float*)d_in[1];   // (P, D) fp32
    float* out = (float*)d_out;                   // (B,)  fp32
    (void)d_ws; (void)ws_size;                    // workspace unused

    som_fused<<<NBLK, 1024, 0, stream>>>(x, proto, out);
}

// Round 7
// 62.790 us; speedup vs baseline: 1.6773x; 1.2555x over previous
//
#include <hip/hip_runtime.h>
#include <hip/hip_bf16.h>

// SOM layer: out[b] = mean_p ||x_b - proto_p||^2
//          = ||x_b||^2 + (1/P)*sum_p||p||^2 - (2/P)*dot(x_b, colsum)
// B=8192, P=1024, D=256, all fp32.
//
// FINAL STRUCTURE (R6 post-mortem): two plain dispatches is the optimum.
//  - R1 3-dispatch (memset+atomics): 69.8 us
//  - R2/R3/R4 2-dispatch variants:   62.85/62.95/62.98 us (within noise)
//  - R5 cooperative single dispatch: 105.3 us (coop launch overhead in graph)
//  - R6 redundant-colsum single:      78.8 us (nblocks x 1MB proto L2 traffic)
// Timed window is dominated by the harness's 268 MB ws re-poison fill
// (~42 us @ ~80% HBM peak) + input restore; kernel internals are inside
// run-to-run noise.
//
// ws layout (floats):
//   ws[g*256 + d]  (g=0..31) : block g's partial colsum over its 32 proto rows
//   ws[32*256 + g]           : block g's partial sum(proto^2)
//
// COHERENCE NOTE (round-3 post-mortem): the cross-kernel ws handoff MUST use
// device(agent)-scope atomics on MI355X. Per-XCD L2s are not cross-coherent;
// plain store->load handoff between kernels is flaky under graph replay
// (first launch passed, replay diverged). Agent-scope atomic stores write
// through to the LLC coherence point; agent-scope loads read from it.

#define SOM_B 8192
#define SOM_P 1024
#define SOM_D 256
#define NPART 32

__device__ __forceinline__ void ws_store(float* p, float v) {
    __hip_atomic_store(p, v, __ATOMIC_RELAXED, __HIP_MEMORY_SCOPE_AGENT);
}
__device__ __forceinline__ float ws_load(const float* p) {
    return __hip_atomic_load(p, __ATOMIC_RELAXED, __HIP_MEMORY_SCOPE_AGENT);
}

// ---- Kernel A: per-block prototype partials (grid=32 x 256 thr) ----
// Block g handles 32 rows; each wave handles 8 rows; lane owns float4 column.
__global__ __launch_bounds__(256) void som_proto_partial(
    const float* __restrict__ proto, float* __restrict__ ws) {
    const int lane = threadIdx.x & 63;
    const int wv   = threadIdx.x >> 6;                 // 0..3
    const int row0 = blockIdx.x * 32 + wv * 8;
    const float4* p4 = (const float4*)proto;           // row stride 64 float4

    float4 cs = {0.f, 0.f, 0.f, 0.f};
    float sq = 0.f;
#pragma unroll
    for (int i = 0; i < 8; ++i) {
        float4 v = p4[(size_t)(row0 + i) * (SOM_D / 4) + lane];
        cs.x += v.x; cs.y += v.y; cs.z += v.z; cs.w += v.w;
        sq   += v.x * v.x + v.y * v.y + v.z * v.z + v.w * v.w;
    }
    __shared__ float4 lds_cs[4][64];
    __shared__ float  lds_sq[4];
#pragma unroll
    for (int off = 32; off; off >>= 1) sq += __shfl_down(sq, off, 64);
    if (lane == 0) lds_sq[wv] = sq;
    lds_cs[wv][lane] = cs;
    __syncthreads();
    if (threadIdx.x < 64) {
        float4 a = lds_cs[0][lane], b = lds_cs[1][lane];
        float4 c = lds_cs[2][lane], d = lds_cs[3][lane];
        float* base = ws + (size_t)blockIdx.x * SOM_D + lane * 4;
        ws_store(base + 0, (a.x + b.x) + (c.x + d.x));
        ws_store(base + 1, (a.y + b.y) + (c.y + d.y));
        ws_store(base + 2, (a.z + b.z) + (c.z + d.z));
        ws_store(base + 3, (a.w + b.w) + (c.w + d.w));
        if (lane == 0)
            ws_store(&ws[NPART * SOM_D + blockIdx.x],
                     (lds_sq[0] + lds_sq[1]) + (lds_sq[2] + lds_sq[3]));
    }
}

// ---- Kernel B: reduce partials + 16 output rows per block (grid=512) ----
__global__ __launch_bounds__(256) void som_out_kernel(
    const float* __restrict__ x, const float* __restrict__ ws,
    float* __restrict__ out) {
    __shared__ float cs[SOM_D];
    __shared__ float sqp_lds;
    const int t    = threadIdx.x;
    const int lane = t & 63;
    const int wv   = t >> 6;

    // Phase 1a: thread t reduces column t over the 32 partial colsums.
    // Agent-scope loads: 64 consecutive addresses per wave-instr, LLC-hit.
    {
        float c = 0.f;
#pragma unroll
        for (int g = 0; g < NPART; ++g) c += ws_load(&ws[g * SOM_D + t]);
        cs[t] = c;
    }
    // Phase 1b: lanes 0..31 of wave 0 reduce the 32 sq partials.
    if (t < 32) {
        float s = ws_load(&ws[NPART * SOM_D + t]);
#pragma unroll
        for (int off = 16; off; off >>= 1) s += __shfl_down(s, off, 32);
        if (t == 0) sqp_lds = s;
    }
    __syncthreads();

    // Phase 2: 16 rows/block, 4 rows/wave, lane owns float4 column.
    const float  sqp = sqp_lds;
    const float4 mv  = ((const float4*)cs)[lane];
    const int    row0 = blockIdx.x * 16 + wv * 4;
    const float4* x4  = (const float4*)x;              // row stride 64 float4

    float sq[4], dt[4];
#pragma unroll
    for (int i = 0; i < 4; ++i) {
        float4 xv = x4[(size_t)(row0 + i) * 64 + lane];
        sq[i] = xv.x * xv.x + xv.y * xv.y + xv.z * xv.z + xv.w * xv.w;
        dt[i] = xv.x * mv.x + xv.y * mv.y + xv.z * mv.z + xv.w * mv.w;
    }
#pragma unroll
    for (int i = 0; i < 4; ++i) {
#pragma unroll
        for (int off = 32; off; off >>= 1) {
            sq[i] += __shfl_down(sq[i], off, 64);
            dt[i] += __shfl_down(dt[i], off, 64);
        }
    }
    if (lane == 0) {
        const float invP = 1.0f / (float)SOM_P;
#pragma unroll
        for (int i = 0; i < 4; ++i)
            out[row0 + i] = sq[i] + (sqp - 2.0f * dt[i]) * invP;
    }
}

extern "C" void kernel_launch(void* const* d_in, const int* in_sizes, int n_in,
                              void* d_out, int out_size, void* d_ws, size_t ws_size,
                              hipStream_t stream) {
    const float* x     = (const float*)d_in[0];   // (B, D) fp32
    const float* proto = (const float*)d_in[1];   // (P, D) fp32
    float* out = (float*)d_out;                   // (B,)  fp32
    float* ws  = (float*)d_ws;                    // partials (~33 KB used)

    som_proto_partial<<<NPART, 256, 0, stream>>>(proto, ws);
    som_out_kernel<<<SOM_B / 16, 256, 0, stream>>>(x, ws, out);
}